// Round 32
// baseline (287.101 us; speedup 1.0000x reference)
//
#include <hip/hip_runtime.h>
#include <hip/hip_bf16.h>
#include <math.h>

#define BATCH 64
#define HW 28
#define PIX 784           // 28*28
#define LATENT 256
#define LABEL 10
#define FEAT 50176        // 64*28*28
#define KS 98             // enc_fc k-chunks (part = 98*16384 floats = xbf cap)
#define KCH 512           // 50176/98
#define TSTR 36           // small-conv LDS row stride

typedef __attribute__((ext_vector_type(8))) short bf16x8;
typedef __attribute__((ext_vector_type(4))) float f32x4;

__device__ __forceinline__ float sgnf(float v) {
    return (v > 0.f) ? 1.f : ((v < 0.f) ? -1.f : 0.f);
}

__device__ __forceinline__ short f2bf(float f) {
    union { float f; unsigned u; } v; v.f = f;
    unsigned r = v.u + 0x7FFF + ((v.u >> 16) & 1);   // RNE
    return (short)(r >> 16);
}
__device__ __forceinline__ float bf2f(short s) {
    union { unsigned u; float f; } v; v.u = ((unsigned)(unsigned short)s) << 16;
    return v.f;
}

// Truncated 3-limb split: v ~= hi + mid + lo with |residual| < 2^-24 |v|.
__device__ __forceinline__ void split3(float v, short &h, short &m, short &l) {
    union { float f; unsigned u; } a; a.f = v;
    h = (short)(a.u >> 16);
    float rh = v - bf2f(h);
    union { float f; unsigned u; } b; b.f = rh;
    m = (short)(b.u >> 16);
    float rm = rh - bf2f(m);
    union { float f; unsigned u; } c; c.f = rm;
    l = (short)(c.u >> 16);
}

// Vector-element refs can't bind to short& on hipcc; scalar temps then assign.
__device__ __forceinline__ void split3x8(float4 a, float4 b,
                                         bf16x8 &h, bf16x8 &m, bf16x8 &l) {
    float vs[8] = {a.x, a.y, a.z, a.w, b.x, b.y, b.z, b.w};
    #pragma unroll
    for (int i = 0; i < 8; ++i) {
        short hh, mm, ll;
        split3(vs[i], hh, mm, ll);
        h[i] = hh; m[i] = mm; l[i] = ll;
    }
}

// ---------------------------------------------------------------------------
// fp32 conv (round-6 proven form). Used for conv1 (IC=1) and ct1 (OC=1).
// ---------------------------------------------------------------------------
template<int G, int FLIP>
__global__ __launch_bounds__(256) void conv5_k(const float* __restrict__ in,
                        const float* __restrict__ w,
                        const float* __restrict__ bias, float* __restrict__ out,
                        int IC, int OC, int relu) {
    int b = blockIdx.x, oc0 = blockIdx.y * G;
    __shared__ float plp[2][32 * TSTR];
    int tid = threadIdx.x;

    for (int t = tid; t < 2 * 32 * TSTR; t += 256) ((float*)plp)[t] = 0.f;

    bool actS = tid < 196;
    int ys = tid / 7, qs = tid % 7;

    int q = tid & 7, yy = tid >> 3;
    bool actC = (q < 7) && (yy < 28);
    int x0 = q * 4;

    float acc[G][4];
    #pragma unroll
    for (int g = 0; g < G; ++g)
        #pragma unroll
        for (int xi = 0; xi < 4; ++xi) acc[g][xi] = 0.f;

    __syncthreads();
    if (actS) {
        float4 v = *(const float4*)&in[((size_t)(b * IC + 0)) * PIX + tid * 4];
        *(float2*)&plp[0][(ys + 2) * TSTR + 4 * qs + 2] = make_float2(v.x, v.y);
        *(float2*)&plp[0][(ys + 2) * TSTR + 4 * qs + 4] = make_float2(v.z, v.w);
    }
    __syncthreads();

    for (int ic = 0; ic < IC; ++ic) {
        float4 vn;
        bool more = (ic + 1) < IC;
        if (more && actS)
            vn = *(const float4*)&in[((size_t)(b * IC + ic + 1)) * PIX + tid * 4];

        const float* tile = plp[ic & 1];
        if (actC) {
            #pragma unroll
            for (int dy = 0; dy < 5; ++dy) {
                float4 ra = *(const float4*)&tile[(yy + dy) * TSTR + x0];
                float4 rb = *(const float4*)&tile[(yy + dy) * TSTR + x0 + 4];
                float rw[8] = {ra.x, ra.y, ra.z, ra.w, rb.x, rb.y, rb.z, rb.w};
                #pragma unroll
                for (int g = 0; g < G; ++g) {
                    #pragma unroll
                    for (int dx = 0; dx < 5; ++dx) {
                        float wv = FLIP
                            ? w[((size_t)ic * OC + (oc0 + g)) * 25 + (4 - dy) * 5 + (4 - dx)]
                            : w[((size_t)(oc0 + g) * IC + ic) * 25 + dy * 5 + dx];
                        #pragma unroll
                        for (int xi = 0; xi < 4; ++xi)
                            acc[g][xi] += rw[xi + dx] * wv;
                    }
                }
            }
        }
        if (more && actS) {
            float* nt = plp[(ic + 1) & 1];
            *(float2*)&nt[(ys + 2) * TSTR + 4 * qs + 2] = make_float2(vn.x, vn.y);
            *(float2*)&nt[(ys + 2) * TSTR + 4 * qs + 4] = make_float2(vn.z, vn.w);
        }
        __syncthreads();
    }

    if (actC) {
        #pragma unroll
        for (int g = 0; g < G; ++g) {
            float bv = bias[oc0 + g];
            float4 o;
            o.x = acc[g][0] + bv;
            o.y = acc[g][1] + bv;
            o.z = acc[g][2] + bv;
            o.w = acc[g][3] + bv;
            if (relu) {
                o.x = fmaxf(o.x, 0.f); o.y = fmaxf(o.y, 0.f);
                o.z = fmaxf(o.z, 0.f); o.w = fmaxf(o.w, 0.f);
            }
            *(float4*)&out[((size_t)(b * OC + (oc0 + g))) * PIX + yy * HW + x0] = o;
        }
    }
}

// ---------------------------------------------------------------------------
// conv2 via MFMA with fp32-equivalent split-bf16 (validated r14; best c2 form).
// ---------------------------------------------------------------------------
__global__ __launch_bounds__(64) void c2_mfma_k(const short* __restrict__ xh,
                        const short* __restrict__ xm, const short* __restrict__ xl,
                        const short* __restrict__ wb,   // [3][25][64][32]
                        const float* __restrict__ bias, float* __restrict__ out) {
    int b = blockIdx.x;
    int t0 = blockIdx.y * 4;
    int lane = threadIdx.x;
    int prow = lane & 15, kgrp = lane >> 4;

    f32x4 acc[4][4];   // [pt][nt]
    #pragma unroll
    for (int pt = 0; pt < 4; ++pt)
        #pragma unroll
        for (int nt = 0; nt < 4; ++nt) acc[pt][nt] = (f32x4){0.f, 0.f, 0.f, 0.f};

    int py[4], px[4];
    bool ptv[4];
    #pragma unroll
    for (int pt = 0; pt < 4; ++pt) {
        int p = (t0 + pt) * 16 + prow;
        ptv[pt] = (t0 + pt) < 49;
        py[pt] = p / 28; px[pt] = p % 28;
    }

    for (int tap = 0; tap < 25; ++tap) {
        int dy = tap / 5 - 2, dx = tap % 5 - 2;
        const short* wt = wb + (size_t)tap * 2048;
        bf16x8 B0[4], B1[4], B2[4];
        #pragma unroll
        for (int nt = 0; nt < 4; ++nt) {
            int off = (nt * 16 + prow) * 32 + kgrp * 8;
            B0[nt] = *(const bf16x8*)&wt[off];
            B1[nt] = *(const bf16x8*)&wt[51200 + off];
            B2[nt] = *(const bf16x8*)&wt[102400 + off];
        }
        #pragma unroll
        for (int pt = 0; pt < 4; ++pt) {
            int ysrc = py[pt] + dy, xsrc = px[pt] + dx;
            bool valid = ptv[pt] && (ysrc >= 0) && (ysrc < 28) && (xsrc >= 0) && (xsrc < 28);
            bf16x8 ah = {0,0,0,0,0,0,0,0}, am = {0,0,0,0,0,0,0,0}, al = {0,0,0,0,0,0,0,0};
            if (valid) {
                size_t o = ((size_t)b * PIX + ysrc * 28 + xsrc) * 32 + kgrp * 8;
                ah = *(const bf16x8*)&xh[o];
                am = *(const bf16x8*)&xm[o];
                al = *(const bf16x8*)&xl[o];
            }
            #pragma unroll
            for (int nt = 0; nt < 4; ++nt) {
                acc[pt][nt] = __builtin_amdgcn_mfma_f32_16x16x32_bf16(ah, B0[nt], acc[pt][nt], 0, 0, 0);
                acc[pt][nt] = __builtin_amdgcn_mfma_f32_16x16x32_bf16(ah, B1[nt], acc[pt][nt], 0, 0, 0);
                acc[pt][nt] = __builtin_amdgcn_mfma_f32_16x16x32_bf16(am, B0[nt], acc[pt][nt], 0, 0, 0);
                acc[pt][nt] = __builtin_amdgcn_mfma_f32_16x16x32_bf16(ah, B2[nt], acc[pt][nt], 0, 0, 0);
                acc[pt][nt] = __builtin_amdgcn_mfma_f32_16x16x32_bf16(am, B1[nt], acc[pt][nt], 0, 0, 0);
                acc[pt][nt] = __builtin_amdgcn_mfma_f32_16x16x32_bf16(al, B0[nt], acc[pt][nt], 0, 0, 0);
            }
        }
    }

    __shared__ float ot[64][17];
    float bv = bias[lane];
    for (int pt = 0; pt < 4; ++pt) {
        if (!ptv[pt]) continue;
        #pragma unroll
        for (int nt = 0; nt < 4; ++nt)
            #pragma unroll
            for (int r = 0; r < 4; ++r)
                ot[nt * 16 + prow][kgrp * 4 + r] = acc[pt][nt][r];
        float* op = &out[((size_t)(b * 64 + lane)) * PIX + (t0 + pt) * 16];
        #pragma unroll
        for (int i = 0; i < 4; ++i) {
            float4 o;
            o.x = fmaxf(ot[lane][i * 4 + 0] + bv, 0.f);
            o.y = fmaxf(ot[lane][i * 4 + 1] + bv, 0.f);
            o.z = fmaxf(ot[lane][i * 4 + 2] + bv, 0.f);
            o.w = fmaxf(ot[lane][i * 4 + 3] + bv, 0.f);
            *(float4*)&op[i * 4] = o;
        }
    }
}

// a1 [b][32][784] fp32 -> xh/xm/xl [b][784][32] bf16 limbs. grid (64,49), 256.
__global__ void xsplit3_k(const float* __restrict__ x, short* __restrict__ xh,
                          short* __restrict__ xm, short* __restrict__ xl) {
    __shared__ float lds[32][17];
    int b = blockIdx.x, pbase = blockIdx.y * 16;
    int t = threadIdx.x;
    if (t < 128) {
        int ic = t >> 2, pj = (t & 3) * 4;
        float4 v = *(const float4*)&x[((size_t)(b * 32 + ic)) * PIX + pbase + pj];
        lds[ic][pj + 0] = v.x; lds[ic][pj + 1] = v.y;
        lds[ic][pj + 2] = v.z; lds[ic][pj + 3] = v.w;
    }
    __syncthreads();
    int p = t >> 4, ic2 = (t & 15) * 2;
    size_t o = ((size_t)b * PIX + pbase + p) * 32 + ic2;
    short2 h, m, l;
    {
        float v = lds[ic2][p];
        short s0 = f2bf(v); float r = v - bf2f(s0);
        short s1 = f2bf(r); float r2 = r - bf2f(s1);
        h.x = s0; m.x = s1; l.x = f2bf(r2);
    }
    {
        float v = lds[ic2 + 1][p];
        short s0 = f2bf(v); float r = v - bf2f(s0);
        short s1 = f2bf(r); float r2 = r - bf2f(s1);
        h.y = s0; m.y = s1; l.y = f2bf(r2);
    }
    *(short2*)&xh[o] = h;
    *(short2*)&xm[o] = m;
    *(short2*)&xl[o] = l;
}

// c2w [64oc][32ic][5][5] -> wb [3][25tap][64oc][32ic] bf16 limbs.
__global__ void wprep3_k(const float* __restrict__ w, short* __restrict__ wb) {
    int j = blockIdx.x * 256 + threadIdx.x;
    if (j < 51200) {
        int ic = j & 31;
        int oc = (j >> 5) & 63;
        int tap = j >> 11;
        float v = w[((size_t)oc * 32 + ic) * 25 + tap];
        short s0 = f2bf(v); float r = v - bf2f(s0);
        short s1 = f2bf(r); float r2 = r - bf2f(s1);
        wb[j] = s0;
        wb[51200 + j] = s1;
        wb[102400 + j] = f2bf(r2);
    }
}

// ---------------------------------------------------------------------------
// ct2 via bf16 MFMA (decoder; validated round 13).
// ---------------------------------------------------------------------------
__global__ __launch_bounds__(64) void ct2_mfma_k(const short* __restrict__ xb,
                        const short* __restrict__ wb,
                        const float* __restrict__ bias, float* __restrict__ out) {
    int b = blockIdx.x;
    int pbase = blockIdx.y * 16;
    int lane = threadIdx.x;
    int prow = lane & 15;
    int kgrp = lane >> 4;
    int p = pbase + prow;
    int py = p / 28, px = p % 28;

    f32x4 acc0 = {0.f, 0.f, 0.f, 0.f};
    f32x4 acc1 = {0.f, 0.f, 0.f, 0.f};

    for (int tap = 0; tap < 25; ++tap) {
        int dy = tap / 5 - 2, dx = tap % 5 - 2;
        int ysrc = py + dy, xsrc = px + dx;
        bool valid = (ysrc >= 0) && (ysrc < 28) && (xsrc >= 0) && (xsrc < 28);
        int ps = ysrc * 28 + xsrc;

        bf16x8 a0 = {0,0,0,0,0,0,0,0}, a1 = {0,0,0,0,0,0,0,0};
        if (valid) {
            const bf16x8* ap = (const bf16x8*)&xb[((size_t)b * PIX + ps) * 64 + kgrp * 8];
            a0 = ap[0];
            a1 = ap[4];
        }
        const short* wt = &wb[(size_t)tap * 32 * 64];
        int oc_l = lane & 15;
        bf16x8 b00 = *(const bf16x8*)&wt[oc_l * 64 + kgrp * 8];
        bf16x8 b01 = *(const bf16x8*)&wt[oc_l * 64 + 32 + kgrp * 8];
        bf16x8 b10 = *(const bf16x8*)&wt[(16 + oc_l) * 64 + kgrp * 8];
        bf16x8 b11 = *(const bf16x8*)&wt[(16 + oc_l) * 64 + 32 + kgrp * 8];

        acc0 = __builtin_amdgcn_mfma_f32_16x16x32_bf16(a0, b00, acc0, 0, 0, 0);
        acc0 = __builtin_amdgcn_mfma_f32_16x16x32_bf16(a1, b01, acc0, 0, 0, 0);
        acc1 = __builtin_amdgcn_mfma_f32_16x16x32_bf16(a0, b10, acc1, 0, 0, 0);
        acc1 = __builtin_amdgcn_mfma_f32_16x16x32_bf16(a1, b11, acc1, 0, 0, 0);
    }

    __shared__ float ot[32][16];
    int drow = (lane >> 4) * 4;
    #pragma unroll
    for (int r = 0; r < 4; ++r) {
        ot[lane & 15][drow + r]        = acc0[r];
        ot[16 + (lane & 15)][drow + r] = acc1[r];
    }
    __syncthreads();
    int oc = lane >> 1, ph = (lane & 1) * 8;
    float bv = bias[oc];
    float4 o0, o1;
    o0.x = fmaxf(ot[oc][ph + 0] + bv, 0.f);
    o0.y = fmaxf(ot[oc][ph + 1] + bv, 0.f);
    o0.z = fmaxf(ot[oc][ph + 2] + bv, 0.f);
    o0.w = fmaxf(ot[oc][ph + 3] + bv, 0.f);
    o1.x = fmaxf(ot[oc][ph + 4] + bv, 0.f);
    o1.y = fmaxf(ot[oc][ph + 5] + bv, 0.f);
    o1.z = fmaxf(ot[oc][ph + 6] + bv, 0.f);
    o1.w = fmaxf(ot[oc][ph + 7] + bv, 0.f);
    float* op = &out[((size_t)(b * 32 + oc)) * PIX + pbase + ph];
    *(float4*)&op[0] = o0;
    *(float4*)&op[4] = o1;
}

__global__ void wprep_k(const float* __restrict__ w, short* __restrict__ wb) {
    int j = blockIdx.x * 256 + threadIdx.x;
    if (j < 25 * 32 * 64) {
        int ic = j & 63;
        int oc = (j >> 6) & 31;
        int tap = j >> 11;
        int dyi = tap / 5, dxi = tap % 5;
        wb[j] = f2bf(w[((size_t)ic * 32 + oc) * 25 + (4 - dyi) * 5 + (4 - dxi)]);
    }
}

// y16 [b][64ic][784] bf16 -> xbf [b][784][64ic] bf16. grid (64,49), 256 thr.
__global__ void xpose16_k(const short* __restrict__ y16, short* __restrict__ xb) {
    __shared__ short lds[64][16];
    int b = blockIdx.x, pbase = blockIdx.y * 16;
    int t = threadIdx.x;
    {
        int ic = t >> 2, pj = (t & 3) * 4;
        short4 v = *(const short4*)&y16[((size_t)(b * 64 + ic)) * PIX + pbase + pj];
        lds[ic][pj + 0] = v.x;
        lds[ic][pj + 1] = v.y;
        lds[ic][pj + 2] = v.z;
        lds[ic][pj + 3] = v.w;
    }
    __syncthreads();
    {
        int p = t >> 4, icq = (t & 15) * 4;
        short4 s;
        s.x = lds[icq + 0][p];
        s.y = lds[icq + 1][p];
        s.z = lds[icq + 2][p];
        s.w = lds[icq + 3][p];
        *(short4*)&xb[((size_t)b * PIX + pbase + p) * 64 + icq] = s;
    }
}

// ---------------------------------------------------------------------------
// Encoder FC via MFMA, split-bf16 fp32-equivalent (round 32 = r30 body,
// KS 56->98). r31 post-mortem: LDS staging + 2 barriers/k-step regressed
// (286.2 vs 281.9) — kernel is memory-LATENCY-bound at 0.875 waves/SIMD,
// not split-VALU-bound. Fix occupancy instead: KCH 896->512 gives grid
// (4, 98) = 392 blocks = 1.53 waves/SIMD (1.75x TLP). Kernel body is the
// r30-passing form unchanged; only the chunk size macro differs.
// grid = (4 n-blocks of 64, 98 k-chunks of 512), block 256 = 4 waves.
// ---------------------------------------------------------------------------
__global__ __launch_bounds__(256) void enc_fc_mfma_k(const float* __restrict__ x,
                              const float* __restrict__ w,
                              float* __restrict__ part) {
    int tid = threadIdx.x;
    int lane = tid & 63, wv = tid >> 6;
    int prow = lane & 15, kgrp = lane >> 4;
    int nb = blockIdx.x * 64 + wv * 16;
    int ks = blockIdx.y;

    f32x4 acc[4];
    #pragma unroll
    for (int mi = 0; mi < 4; ++mi) acc[mi] = (f32x4){0.f, 0.f, 0.f, 0.f};

    const float* wrow = &w[(size_t)(nb + prow) * FEAT];
    int k0 = ks * KCH;

    for (int kk = 0; kk < KCH; kk += 32) {
        int kof = k0 + kk + kgrp * 8;
        bf16x8 wh, wm, wl;
        {
            float4 wa = *(const float4*)&wrow[kof];
            float4 wb4 = *(const float4*)&wrow[kof + 4];
            split3x8(wa, wb4, wh, wm, wl);
        }
        #pragma unroll
        for (int mi = 0; mi < 4; ++mi) {
            const float* xr = &x[(size_t)(mi * 16 + prow) * FEAT + kof];
            float4 xa = *(const float4*)&xr[0];
            float4 xb4 = *(const float4*)&xr[4];
            bf16x8 ah, am, al;
            split3x8(xa, xb4, ah, am, al);
            // c2's validated 6-product fp32-equivalent sequence
            acc[mi] = __builtin_amdgcn_mfma_f32_16x16x32_bf16(ah, wh, acc[mi], 0, 0, 0);
            acc[mi] = __builtin_amdgcn_mfma_f32_16x16x32_bf16(ah, wm, acc[mi], 0, 0, 0);
            acc[mi] = __builtin_amdgcn_mfma_f32_16x16x32_bf16(am, wh, acc[mi], 0, 0, 0);
            acc[mi] = __builtin_amdgcn_mfma_f32_16x16x32_bf16(ah, wl, acc[mi], 0, 0, 0);
            acc[mi] = __builtin_amdgcn_mfma_f32_16x16x32_bf16(am, wm, acc[mi], 0, 0, 0);
            acc[mi] = __builtin_amdgcn_mfma_f32_16x16x32_bf16(al, wh, acc[mi], 0, 0, 0);
        }
    }

    // part[(ks*BATCH + m)*LATENT + n]; lanes 0-15 write 16 consecutive n (64B).
    #pragma unroll
    for (int mi = 0; mi < 4; ++mi)
        #pragma unroll
        for (int r = 0; r < 4; ++r)
            part[(size_t)(ks * BATCH + mi * 16 + kgrp * 4 + r) * LATENT + nb + prow]
                = acc[mi][r];
}

// grid 64 (m), block 256 (n): z = tanh(sum_ks part + b); emit 2-limb bf16 of
// atanh(z) in [m][k] layout for the MFMA decoder FC.
__global__ void enc_fc_fin_k(const float* __restrict__ part, const float* __restrict__ bias,
                             float* __restrict__ z, short* __restrict__ xah,
                             short* __restrict__ xam) {
    int m = blockIdx.x;
    int n = threadIdx.x;
    int idx = m * 256 + n;
    float a = bias[n];
    for (int ksi = 0; ksi < KS; ++ksi) a += part[(size_t)ksi * BATCH * LATENT + idx];
    float zv = tanhf(a);
    z[idx] = zv;
    float xv = atanhf(zv);
    short h = f2bf(xv);
    xah[idx] = h;
    xam[idx] = f2bf(xv - bf2f(h));
}

// ---------------------------------------------------------------------------
// Hopfield weight
// ---------------------------------------------------------------------------
__global__ void hop_rho_k(const float* __restrict__ ll, float* __restrict__ rho_out) {
    float p = 0.f;
    for (int t = threadIdx.x; t < LABEL * LATENT; t += 256) p += sgnf(ll[t]);
    __shared__ float red[8];
    for (int o = 32; o; o >>= 1) p += __shfl_down(p, o, 64);
    if ((threadIdx.x & 63) == 0) red[threadIdx.x >> 6] = p;
    __syncthreads();
    if (threadIdx.x == 0)
        rho_out[0] = (red[0] + red[1] + red[2] + red[3]) / (float)(LABEL * LATENT);
}

__global__ void hop_w_k(const float* __restrict__ ll, const float* __restrict__ rho_p,
                        float* __restrict__ wout) {
    int i = blockIdx.x, j = threadIdx.x;
    float rho = rho_p[0];
    float acc = 0.f;
    #pragma unroll
    for (int l = 0; l < LABEL; ++l) {
        float a = sgnf(ll[l * LATENT + i]) - rho;
        float b = sgnf(ll[l * LATENT + j]) - rho;
        acc += a * b;
    }
    wout[i * LATENT + j] = (i == j) ? 0.f : acc / 10.f;
}

// ---------------------------------------------------------------------------
// Cluster iteration + cluster softmax head.
// ---------------------------------------------------------------------------
__global__ __launch_bounds__(1024) void cluster_k(const float* __restrict__ z,
                          const float* __restrict__ w,
                          const float* __restrict__ ll, float* __restrict__ out) {
    int b = blockIdx.x;
    int t = threadIdx.x;
    int i = t & 255;
    int q = t >> 8;
    int lane = t & 63;
    int wvid = t >> 6;

    __shared__ float s_sh[LATENT];
    __shared__ float part[1024];
    __shared__ float red[4];
    __shared__ float cflag[4];
    __shared__ int ctl_sh;
    __shared__ float logit[LABEL];

    float wreg[64];
    #pragma unroll
    for (int jj = 0; jj < 64; ++jj)
        wreg[jj] = w[(q * 64 + jj) * LATENT + i];

    float s_cur = 0.f, s_old = 2.f, v = 0.f;
    float e_prev = 0.f;
    if (q == 0) {
        s_cur = sgnf(z[b * LATENT + i]);
        s_sh[i] = s_cur;
    }
    __syncthreads();

    {
        float p0 = 0.f, p1 = 0.f;
        #pragma unroll
        for (int jj = 0; jj < 64; jj += 2) {
            p0 += wreg[jj]     * s_sh[q * 64 + jj];
            p1 += wreg[jj + 1] * s_sh[q * 64 + jj + 1];
        }
        part[t] = p0 + p1;
    }
    __syncthreads();
    if (q == 0) {
        v = part[i] + part[i + 256] + part[i + 512] + part[i + 768];
        float p = s_cur * v;
        #pragma unroll
        for (int o = 32; o; o >>= 1) p += __shfl_down(p, o, 64);
        if (lane == 0) red[wvid] = p;
    }
    __syncthreads();
    if (t == 0) e_prev = -(red[0] + red[1] + red[2] + red[3]);

    for (int it = 0; it < LATENT; ++it) {
        if (q == 0) {
            float ns = sgnf(v);
            unsigned long long m = __ballot(ns == s_old);
            if (lane == 0) cflag[wvid] = (m == ~0ull) ? 1.f : 0.f;
            s_sh[i] = ns;
            s_old = s_cur;
            s_cur = ns;
        }
        __syncthreads();
        {
            float p0 = 0.f, p1 = 0.f;
            #pragma unroll
            for (int jj = 0; jj < 64; jj += 2) {
                p0 += wreg[jj]     * s_sh[q * 64 + jj];
                p1 += wreg[jj + 1] * s_sh[q * 64 + jj + 1];
            }
            part[t] = p0 + p1;
        }
        __syncthreads();
        if (q == 0) {
            v = part[i] + part[i + 256] + part[i + 512] + part[i + 768];
            float p = s_cur * v;
            #pragma unroll
            for (int o = 32; o; o >>= 1) p += __shfl_down(p, o, 64);
            if (lane == 0) red[wvid] = p;
        }
        __syncthreads();
        if (t == 0) {
            float e = -(red[0] + red[1] + red[2] + red[3]);
            int c = 0;
            if (e == e_prev) c = 1;
            else if (it >= 1 && cflag[0] != 0.f && cflag[1] != 0.f &&
                     cflag[2] != 0.f && cflag[3] != 0.f)
                c = (((LATENT - 1 - it) & 1) == 0) ? 2 : 3;
            else e_prev = e;
            ctl_sh = c;
        }
        __syncthreads();
        int c = ctl_sh;
        if (c != 0) {
            if (c == 3 && q == 0) s_sh[i] = s_old;
            break;
        }
    }
    __syncthreads();

    if (wvid < LABEL) {
        float p = 0.f;
        #pragma unroll
        for (int r = 0; r < 4; ++r)
            p += s_sh[r * 64 + lane] * ll[wvid * LATENT + r * 64 + lane];
        #pragma unroll
        for (int o = 32; o; o >>= 1) p += __shfl_down(p, o, 64);
        if (lane == 0) logit[wvid] = p;
    }
    __syncthreads();
    if (t == 0) {
        float mx = logit[0];
        for (int c = 1; c < LABEL; ++c) mx = fmaxf(mx, logit[c]);
        float ex[LABEL];
        float s = 0.f;
        for (int c = 0; c < LABEL; ++c) { ex[c] = expf(logit[c] - mx); s += ex[c]; }
        for (int c = 0; c < LABEL; ++c) out[b * LABEL + c] = ex[c] / s;
    }
}

__device__ __forceinline__ float block_sum256(float p, float* red) {
    __syncthreads();
    for (int o = 32; o; o >>= 1) p += __shfl_down(p, o, 64);
    if ((threadIdx.x & 63) == 0) red[threadIdx.x >> 6] = p;
    __syncthreads();
    return red[0] + red[1] + red[2] + red[3];
}

__global__ void class_k(const float* __restrict__ z, const float* __restrict__ smw,
                        const float* __restrict__ smb, float* __restrict__ out) {
    int b = blockIdx.x;
    int i = threadIdx.x;
    __shared__ float red[8];
    __shared__ float logit[LABEL];
    float zi = z[b * LATENT + i];
    for (int c = 0; c < LABEL; ++c) {
        float p = zi * smw[c * LATENT + i];
        float t = block_sum256(p, red);
        if (i == 0) logit[c] = t + smb[c];
    }
    __syncthreads();
    if (i == 0) {
        float mx = logit[0];
        for (int c = 1; c < LABEL; ++c) mx = fmaxf(mx, logit[c]);
        float ex[LABEL];
        float s = 0.f;
        for (int c = 0; c < LABEL; ++c) { ex[c] = expf(logit[c] - mx); s += ex[c]; }
        for (int c = 0; c < LABEL; ++c) out[b * LABEL + c] = ex[c] / s;
    }
}

// ---------------------------------------------------------------------------
// Decoder FC via MFMA: y16[m][n] = bf16( (xh+xm)[m][k] @ bf16(w)[n][k] + b ).
// ---------------------------------------------------------------------------
__global__ __launch_bounds__(256) void dec_fc_mfma_k(const short* __restrict__ xah,
                         const short* __restrict__ xam,
                         const float* __restrict__ w,
                         const float* __restrict__ bias, short* __restrict__ y16) {
    int tid = threadIdx.x;
    int lane = tid & 63, wv = tid >> 6;
    int prow = lane & 15, kgrp = lane >> 4;
    int n0 = blockIdx.x * 64;
    int nb = n0 + wv * 16;

    f32x4 acc[4];
    #pragma unroll
    for (int mi = 0; mi < 4; ++mi) acc[mi] = (f32x4){0.f, 0.f, 0.f, 0.f};

    for (int kc = 0; kc < 8; ++kc) {
        int kof = kc * 32 + kgrp * 8;
        const float* wp = &w[(size_t)(nb + prow) * LATENT + kof];
        float4 w0 = *(const float4*)&wp[0];
        float4 w1 = *(const float4*)&wp[4];
        bf16x8 bf;
        bf[0] = f2bf(w0.x); bf[1] = f2bf(w0.y); bf[2] = f2bf(w0.z); bf[3] = f2bf(w0.w);
        bf[4] = f2bf(w1.x); bf[5] = f2bf(w1.y); bf[6] = f2bf(w1.z); bf[7] = f2bf(w1.w);
        #pragma unroll
        for (int mi = 0; mi < 4; ++mi) {
            bf16x8 ah = *(const bf16x8*)&xah[(mi * 16 + prow) * LATENT + kof];
            bf16x8 am = *(const bf16x8*)&xam[(mi * 16 + prow) * LATENT + kof];
            acc[mi] = __builtin_amdgcn_mfma_f32_16x16x32_bf16(ah, bf, acc[mi], 0, 0, 0);
            acc[mi] = __builtin_amdgcn_mfma_f32_16x16x32_bf16(am, bf, acc[mi], 0, 0, 0);
        }
    }

    // epilogue: stage bf16 tile [64m][64n] in LDS, coalesced 64B-group stores
    __shared__ short ot[64 * 72];   // stride 72 shorts = 144B (16B-aligned rows)
    float bv = bias[nb + prow];
    #pragma unroll
    for (int mi = 0; mi < 4; ++mi)
        #pragma unroll
        for (int r = 0; r < 4; ++r) {
            int m = mi * 16 + kgrp * 4 + r;
            ot[m * 72 + wv * 16 + prow] = f2bf(acc[mi][r] + bv);
        }
    __syncthreads();
    int m = tid >> 2, q = tid & 3;
    #pragma unroll
    for (int i = 0; i < 2; ++i) {
        *(int4*)&y16[(size_t)m * FEAT + n0 + i * 32 + q * 8] =
            *(int4*)&ot[m * 72 + i * 32 + q * 8];
    }
}

// ---------------------------------------------------------------------------
extern "C" void kernel_launch(void* const* d_in, const int* in_sizes, int n_in,
                              void* d_out, int out_size, void* d_ws, size_t ws_size,
                              hipStream_t stream) {
    const float* images   = (const float*)d_in[0];
    const float* c1w      = (const float*)d_in[1];
    const float* c1b      = (const float*)d_in[2];
    const float* c2w      = (const float*)d_in[3];
    const float* c2b      = (const float*)d_in[4];
    const float* efw      = (const float*)d_in[5];
    const float* efb      = (const float*)d_in[6];
    const float* dfw      = (const float*)d_in[7];
    const float* dfb      = (const float*)d_in[8];
    const float* ct2w     = (const float*)d_in[9];
    const float* ct2b     = (const float*)d_in[10];
    const float* ct1w     = (const float*)d_in[11];
    const float* ct1b     = (const float*)d_in[12];
    const float* smw      = (const float*)d_in[13];
    const float* smb      = (const float*)d_in[14];
    const float* ll       = (const float*)d_in[15];

    float* out = (float*)d_out;
    float* ws  = (float*)d_ws;

    // ws layout (floats)
    float* big0 = ws;                                  // 3211264 (a2; y16 bf16 aliases after enc)
    float* big1 = ws + 3211264;                        // 1605632 (a1 / ct2 out)
    float* z    = ws + 3211264 + 1605632 + 458752;     // 16384
    float* whop = z + BATCH * LATENT;                  // 65536
    float* rho  = whop + LATENT * LATENT;              // 4
    float* xsa  = rho + 4;                             // 16384 (holds xah/xam shorts)
    short* xah  = (short*)xsa;                         // 16384 shorts
    short* xam  = xah + 16384;                         // 16384 shorts
    short* xbf  = (short*)(xsa + 16384);               // 3211264 shorts region
    short* wbf  = (short*)(xsa + 16384 + 1605632);     // 51200 shorts (ct2 w)
    short* xh3  = xbf;                                 // conv2 hi limb (dead before part)
    short* xm3  = xbf + 1605632;                       // conv2 mid limb
    short* xl3  = (short*)(xsa + 16384 + 1605632 + 25600);   // 1605632 shorts
    short* wb3  = xl3 + 1605632;                       // 153600 shorts
    short* y16  = (short*)big0;                        // big0 dead after enc_fc
    // enc_fc partials: 98*16384 = 1605632 floats = the xbf region EXACTLY
    // (ends at wbf, whose lifetime is disjoint: wprep_k runs after fin).
    float* part = (float*)xbf;

    // encoder (conv1 fp32; conv2 + enc_fc split-bf16 MFMA = fp32-equivalent)
    conv5_k<4,0><<<dim3(BATCH, 8), 256, 0, stream>>>(images, c1w, c1b, big1, 1, 32, 1);
    wprep3_k<<<200, 256, 0, stream>>>(c2w, wb3);
    xsplit3_k<<<dim3(BATCH, 49), 256, 0, stream>>>(big1, xh3, xm3, xl3);
    c2_mfma_k<<<dim3(BATCH, 13), 64, 0, stream>>>(xh3, xm3, xl3, wb3, c2b, big0);
    enc_fc_mfma_k<<<dim3(4, KS), 256, 0, stream>>>(big0, efw, part);
    enc_fc_fin_k<<<BATCH, 256, 0, stream>>>(part, efb, z, xah, xam);

    // hopfield
    hop_rho_k<<<1, 256, 0, stream>>>(ll, rho);
    hop_w_k<<<LATENT, 256, 0, stream>>>(ll, rho, whop);
    cluster_k<<<BATCH, 1024, 0, stream>>>(z, whop, ll, out);           // cluster_probs
    class_k<<<BATCH, 256, 0, stream>>>(z, smw, smb, out + 640);        // class_probs

    // decoder (dec_fc MFMA bf16-out; ct2 bf16 MFMA)
    wprep_k<<<200, 256, 0, stream>>>(ct2w, wbf);
    dec_fc_mfma_k<<<FEAT / 64, 256, 0, stream>>>(xah, xam, dfw, dfb, y16);
    xpose16_k<<<dim3(BATCH, 49), 256, 0, stream>>>(y16, xbf);
    ct2_mfma_k<<<dim3(BATCH, 49), 64, 0, stream>>>(xbf, wbf, ct2b, big1);
    conv5_k<1,1><<<dim3(BATCH, 1), 256, 0, stream>>>(big1, ct1w, ct1b, out + 1280, 32, 1, 0);
}

// Round 33
// 280.635 us; speedup vs baseline: 1.0230x; 1.0230x over previous
//
#include <hip/hip_runtime.h>
#include <hip/hip_bf16.h>
#include <math.h>

#define BATCH 64
#define HW 28
#define PIX 784           // 28*28
#define LATENT 256
#define LABEL 10
#define FEAT 50176        // 64*28*28
#define KS 56
#define KCH 896           // 50176/56
#define TSTR 36           // small-conv LDS row stride

typedef __attribute__((ext_vector_type(8))) short bf16x8;
typedef __attribute__((ext_vector_type(4))) float f32x4;

__device__ __forceinline__ float sgnf(float v) {
    return (v > 0.f) ? 1.f : ((v < 0.f) ? -1.f : 0.f);
}

__device__ __forceinline__ short f2bf(float f) {
    union { float f; unsigned u; } v; v.f = f;
    unsigned r = v.u + 0x7FFF + ((v.u >> 16) & 1);   // RNE
    return (short)(r >> 16);
}
__device__ __forceinline__ float bf2f(short s) {
    union { unsigned u; float f; } v; v.u = ((unsigned)(unsigned short)s) << 16;
    return v.f;
}

// Truncated 3-limb split: v ~= hi + mid + lo with |residual| < 2^-24 |v|.
__device__ __forceinline__ void split3(float v, short &h, short &m, short &l) {
    union { float f; unsigned u; } a; a.f = v;
    h = (short)(a.u >> 16);
    float rh = v - bf2f(h);
    union { float f; unsigned u; } b; b.f = rh;
    m = (short)(b.u >> 16);
    float rm = rh - bf2f(m);
    union { float f; unsigned u; } c; c.f = rm;
    l = (short)(c.u >> 16);
}

// Vector-element refs can't bind to short& on hipcc; scalar temps then assign.
__device__ __forceinline__ void split3x8(float4 a, float4 b,
                                         bf16x8 &h, bf16x8 &m, bf16x8 &l) {
    float vs[8] = {a.x, a.y, a.z, a.w, b.x, b.y, b.z, b.w};
    #pragma unroll
    for (int i = 0; i < 8; ++i) {
        short hh, mm, ll;
        split3(vs[i], hh, mm, ll);
        h[i] = hh; m[i] = mm; l[i] = ll;
    }
}

// ---------------------------------------------------------------------------
// fp32 conv (round-6 proven form). Used for conv1 (IC=1) and ct1 (OC=1).
// ---------------------------------------------------------------------------
template<int G, int FLIP>
__global__ __launch_bounds__(256) void conv5_k(const float* __restrict__ in,
                        const float* __restrict__ w,
                        const float* __restrict__ bias, float* __restrict__ out,
                        int IC, int OC, int relu) {
    int b = blockIdx.x, oc0 = blockIdx.y * G;
    __shared__ float plp[2][32 * TSTR];
    int tid = threadIdx.x;

    for (int t = tid; t < 2 * 32 * TSTR; t += 256) ((float*)plp)[t] = 0.f;

    bool actS = tid < 196;
    int ys = tid / 7, qs = tid % 7;

    int q = tid & 7, yy = tid >> 3;
    bool actC = (q < 7) && (yy < 28);
    int x0 = q * 4;

    float acc[G][4];
    #pragma unroll
    for (int g = 0; g < G; ++g)
        #pragma unroll
        for (int xi = 0; xi < 4; ++xi) acc[g][xi] = 0.f;

    __syncthreads();
    if (actS) {
        float4 v = *(const float4*)&in[((size_t)(b * IC + 0)) * PIX + tid * 4];
        *(float2*)&plp[0][(ys + 2) * TSTR + 4 * qs + 2] = make_float2(v.x, v.y);
        *(float2*)&plp[0][(ys + 2) * TSTR + 4 * qs + 4] = make_float2(v.z, v.w);
    }
    __syncthreads();

    for (int ic = 0; ic < IC; ++ic) {
        float4 vn;
        bool more = (ic + 1) < IC;
        if (more && actS)
            vn = *(const float4*)&in[((size_t)(b * IC + ic + 1)) * PIX + tid * 4];

        const float* tile = plp[ic & 1];
        if (actC) {
            #pragma unroll
            for (int dy = 0; dy < 5; ++dy) {
                float4 ra = *(const float4*)&tile[(yy + dy) * TSTR + x0];
                float4 rb = *(const float4*)&tile[(yy + dy) * TSTR + x0 + 4];
                float rw[8] = {ra.x, ra.y, ra.z, ra.w, rb.x, rb.y, rb.z, rb.w};
                #pragma unroll
                for (int g = 0; g < G; ++g) {
                    #pragma unroll
                    for (int dx = 0; dx < 5; ++dx) {
                        float wv = FLIP
                            ? w[((size_t)ic * OC + (oc0 + g)) * 25 + (4 - dy) * 5 + (4 - dx)]
                            : w[((size_t)(oc0 + g) * IC + ic) * 25 + dy * 5 + dx];
                        #pragma unroll
                        for (int xi = 0; xi < 4; ++xi)
                            acc[g][xi] += rw[xi + dx] * wv;
                    }
                }
            }
        }
        if (more && actS) {
            float* nt = plp[(ic + 1) & 1];
            *(float2*)&nt[(ys + 2) * TSTR + 4 * qs + 2] = make_float2(vn.x, vn.y);
            *(float2*)&nt[(ys + 2) * TSTR + 4 * qs + 4] = make_float2(vn.z, vn.w);
        }
        __syncthreads();
    }

    if (actC) {
        #pragma unroll
        for (int g = 0; g < G; ++g) {
            float bv = bias[oc0 + g];
            float4 o;
            o.x = acc[g][0] + bv;
            o.y = acc[g][1] + bv;
            o.z = acc[g][2] + bv;
            o.w = acc[g][3] + bv;
            if (relu) {
                o.x = fmaxf(o.x, 0.f); o.y = fmaxf(o.y, 0.f);
                o.z = fmaxf(o.z, 0.f); o.w = fmaxf(o.w, 0.f);
            }
            *(float4*)&out[((size_t)(b * OC + (oc0 + g))) * PIX + yy * HW + x0] = o;
        }
    }
}

// ---------------------------------------------------------------------------
// conv2 via MFMA with fp32-equivalent split-bf16 (validated r14; best c2 form).
// ---------------------------------------------------------------------------
__global__ __launch_bounds__(64) void c2_mfma_k(const short* __restrict__ xh,
                        const short* __restrict__ xm, const short* __restrict__ xl,
                        const short* __restrict__ wb,   // [3][25][64][32]
                        const float* __restrict__ bias, float* __restrict__ out) {
    int b = blockIdx.x;
    int t0 = blockIdx.y * 4;
    int lane = threadIdx.x;
    int prow = lane & 15, kgrp = lane >> 4;

    f32x4 acc[4][4];   // [pt][nt]
    #pragma unroll
    for (int pt = 0; pt < 4; ++pt)
        #pragma unroll
        for (int nt = 0; nt < 4; ++nt) acc[pt][nt] = (f32x4){0.f, 0.f, 0.f, 0.f};

    int py[4], px[4];
    bool ptv[4];
    #pragma unroll
    for (int pt = 0; pt < 4; ++pt) {
        int p = (t0 + pt) * 16 + prow;
        ptv[pt] = (t0 + pt) < 49;
        py[pt] = p / 28; px[pt] = p % 28;
    }

    for (int tap = 0; tap < 25; ++tap) {
        int dy = tap / 5 - 2, dx = tap % 5 - 2;
        const short* wt = wb + (size_t)tap * 2048;
        bf16x8 B0[4], B1[4], B2[4];
        #pragma unroll
        for (int nt = 0; nt < 4; ++nt) {
            int off = (nt * 16 + prow) * 32 + kgrp * 8;
            B0[nt] = *(const bf16x8*)&wt[off];
            B1[nt] = *(const bf16x8*)&wt[51200 + off];
            B2[nt] = *(const bf16x8*)&wt[102400 + off];
        }
        #pragma unroll
        for (int pt = 0; pt < 4; ++pt) {
            int ysrc = py[pt] + dy, xsrc = px[pt] + dx;
            bool valid = ptv[pt] && (ysrc >= 0) && (ysrc < 28) && (xsrc >= 0) && (xsrc < 28);
            bf16x8 ah = {0,0,0,0,0,0,0,0}, am = {0,0,0,0,0,0,0,0}, al = {0,0,0,0,0,0,0,0};
            if (valid) {
                size_t o = ((size_t)b * PIX + ysrc * 28 + xsrc) * 32 + kgrp * 8;
                ah = *(const bf16x8*)&xh[o];
                am = *(const bf16x8*)&xm[o];
                al = *(const bf16x8*)&xl[o];
            }
            #pragma unroll
            for (int nt = 0; nt < 4; ++nt) {
                acc[pt][nt] = __builtin_amdgcn_mfma_f32_16x16x32_bf16(ah, B0[nt], acc[pt][nt], 0, 0, 0);
                acc[pt][nt] = __builtin_amdgcn_mfma_f32_16x16x32_bf16(ah, B1[nt], acc[pt][nt], 0, 0, 0);
                acc[pt][nt] = __builtin_amdgcn_mfma_f32_16x16x32_bf16(am, B0[nt], acc[pt][nt], 0, 0, 0);
                acc[pt][nt] = __builtin_amdgcn_mfma_f32_16x16x32_bf16(ah, B2[nt], acc[pt][nt], 0, 0, 0);
                acc[pt][nt] = __builtin_amdgcn_mfma_f32_16x16x32_bf16(am, B1[nt], acc[pt][nt], 0, 0, 0);
                acc[pt][nt] = __builtin_amdgcn_mfma_f32_16x16x32_bf16(al, B0[nt], acc[pt][nt], 0, 0, 0);
            }
        }
    }

    __shared__ float ot[64][17];
    float bv = bias[lane];
    for (int pt = 0; pt < 4; ++pt) {
        if (!ptv[pt]) continue;
        #pragma unroll
        for (int nt = 0; nt < 4; ++nt)
            #pragma unroll
            for (int r = 0; r < 4; ++r)
                ot[nt * 16 + prow][kgrp * 4 + r] = acc[pt][nt][r];
        float* op = &out[((size_t)(b * 64 + lane)) * PIX + (t0 + pt) * 16];
        #pragma unroll
        for (int i = 0; i < 4; ++i) {
            float4 o;
            o.x = fmaxf(ot[lane][i * 4 + 0] + bv, 0.f);
            o.y = fmaxf(ot[lane][i * 4 + 1] + bv, 0.f);
            o.z = fmaxf(ot[lane][i * 4 + 2] + bv, 0.f);
            o.w = fmaxf(ot[lane][i * 4 + 3] + bv, 0.f);
            *(float4*)&op[i * 4] = o;
        }
    }
}

// a1 [b][32][784] fp32 -> xh/xm/xl [b][784][32] bf16 limbs. grid (64,49), 256.
__global__ void xsplit3_k(const float* __restrict__ x, short* __restrict__ xh,
                          short* __restrict__ xm, short* __restrict__ xl) {
    __shared__ float lds[32][17];
    int b = blockIdx.x, pbase = blockIdx.y * 16;
    int t = threadIdx.x;
    if (t < 128) {
        int ic = t >> 2, pj = (t & 3) * 4;
        float4 v = *(const float4*)&x[((size_t)(b * 32 + ic)) * PIX + pbase + pj];
        lds[ic][pj + 0] = v.x; lds[ic][pj + 1] = v.y;
        lds[ic][pj + 2] = v.z; lds[ic][pj + 3] = v.w;
    }
    __syncthreads();
    int p = t >> 4, ic2 = (t & 15) * 2;
    size_t o = ((size_t)b * PIX + pbase + p) * 32 + ic2;
    short2 h, m, l;
    {
        float v = lds[ic2][p];
        short s0 = f2bf(v); float r = v - bf2f(s0);
        short s1 = f2bf(r); float r2 = r - bf2f(s1);
        h.x = s0; m.x = s1; l.x = f2bf(r2);
    }
    {
        float v = lds[ic2 + 1][p];
        short s0 = f2bf(v); float r = v - bf2f(s0);
        short s1 = f2bf(r); float r2 = r - bf2f(s1);
        h.y = s0; m.y = s1; l.y = f2bf(r2);
    }
    *(short2*)&xh[o] = h;
    *(short2*)&xm[o] = m;
    *(short2*)&xl[o] = l;
}

// c2w [64oc][32ic][5][5] -> wb [3][25tap][64oc][32ic] bf16 limbs.
__global__ void wprep3_k(const float* __restrict__ w, short* __restrict__ wb) {
    int j = blockIdx.x * 256 + threadIdx.x;
    if (j < 51200) {
        int ic = j & 31;
        int oc = (j >> 5) & 63;
        int tap = j >> 11;
        float v = w[((size_t)oc * 32 + ic) * 25 + tap];
        short s0 = f2bf(v); float r = v - bf2f(s0);
        short s1 = f2bf(r); float r2 = r - bf2f(s1);
        wb[j] = s0;
        wb[51200 + j] = s1;
        wb[102400 + j] = f2bf(r2);
    }
}

// ---------------------------------------------------------------------------
// ct2 via bf16 MFMA (decoder; validated round 13).
// ---------------------------------------------------------------------------
__global__ __launch_bounds__(64) void ct2_mfma_k(const short* __restrict__ xb,
                        const short* __restrict__ wb,
                        const float* __restrict__ bias, float* __restrict__ out) {
    int b = blockIdx.x;
    int pbase = blockIdx.y * 16;
    int lane = threadIdx.x;
    int prow = lane & 15;
    int kgrp = lane >> 4;
    int p = pbase + prow;
    int py = p / 28, px = p % 28;

    f32x4 acc0 = {0.f, 0.f, 0.f, 0.f};
    f32x4 acc1 = {0.f, 0.f, 0.f, 0.f};

    for (int tap = 0; tap < 25; ++tap) {
        int dy = tap / 5 - 2, dx = tap % 5 - 2;
        int ysrc = py + dy, xsrc = px + dx;
        bool valid = (ysrc >= 0) && (ysrc < 28) && (xsrc >= 0) && (xsrc < 28);
        int ps = ysrc * 28 + xsrc;

        bf16x8 a0 = {0,0,0,0,0,0,0,0}, a1 = {0,0,0,0,0,0,0,0};
        if (valid) {
            const bf16x8* ap = (const bf16x8*)&xb[((size_t)b * PIX + ps) * 64 + kgrp * 8];
            a0 = ap[0];
            a1 = ap[4];
        }
        const short* wt = &wb[(size_t)tap * 32 * 64];
        int oc_l = lane & 15;
        bf16x8 b00 = *(const bf16x8*)&wt[oc_l * 64 + kgrp * 8];
        bf16x8 b01 = *(const bf16x8*)&wt[oc_l * 64 + 32 + kgrp * 8];
        bf16x8 b10 = *(const bf16x8*)&wt[(16 + oc_l) * 64 + kgrp * 8];
        bf16x8 b11 = *(const bf16x8*)&wt[(16 + oc_l) * 64 + 32 + kgrp * 8];

        acc0 = __builtin_amdgcn_mfma_f32_16x16x32_bf16(a0, b00, acc0, 0, 0, 0);
        acc0 = __builtin_amdgcn_mfma_f32_16x16x32_bf16(a1, b01, acc0, 0, 0, 0);
        acc1 = __builtin_amdgcn_mfma_f32_16x16x32_bf16(a0, b10, acc1, 0, 0, 0);
        acc1 = __builtin_amdgcn_mfma_f32_16x16x32_bf16(a1, b11, acc1, 0, 0, 0);
    }

    __shared__ float ot[32][16];
    int drow = (lane >> 4) * 4;
    #pragma unroll
    for (int r = 0; r < 4; ++r) {
        ot[lane & 15][drow + r]        = acc0[r];
        ot[16 + (lane & 15)][drow + r] = acc1[r];
    }
    __syncthreads();
    int oc = lane >> 1, ph = (lane & 1) * 8;
    float bv = bias[oc];
    float4 o0, o1;
    o0.x = fmaxf(ot[oc][ph + 0] + bv, 0.f);
    o0.y = fmaxf(ot[oc][ph + 1] + bv, 0.f);
    o0.z = fmaxf(ot[oc][ph + 2] + bv, 0.f);
    o0.w = fmaxf(ot[oc][ph + 3] + bv, 0.f);
    o1.x = fmaxf(ot[oc][ph + 4] + bv, 0.f);
    o1.y = fmaxf(ot[oc][ph + 5] + bv, 0.f);
    o1.z = fmaxf(ot[oc][ph + 6] + bv, 0.f);
    o1.w = fmaxf(ot[oc][ph + 7] + bv, 0.f);
    float* op = &out[((size_t)(b * 32 + oc)) * PIX + pbase + ph];
    *(float4*)&op[0] = o0;
    *(float4*)&op[4] = o1;
}

__global__ void wprep_k(const float* __restrict__ w, short* __restrict__ wb) {
    int j = blockIdx.x * 256 + threadIdx.x;
    if (j < 25 * 32 * 64) {
        int ic = j & 63;
        int oc = (j >> 6) & 31;
        int tap = j >> 11;
        int dyi = tap / 5, dxi = tap % 5;
        wb[j] = f2bf(w[((size_t)ic * 32 + oc) * 25 + (4 - dyi) * 5 + (4 - dxi)]);
    }
}

// y16 [b][64ic][784] bf16 -> xbf [b][784][64ic] bf16. grid (64,49), 256 thr.
__global__ void xpose16_k(const short* __restrict__ y16, short* __restrict__ xb) {
    __shared__ short lds[64][16];
    int b = blockIdx.x, pbase = blockIdx.y * 16;
    int t = threadIdx.x;
    {
        int ic = t >> 2, pj = (t & 3) * 4;
        short4 v = *(const short4*)&y16[((size_t)(b * 64 + ic)) * PIX + pbase + pj];
        lds[ic][pj + 0] = v.x;
        lds[ic][pj + 1] = v.y;
        lds[ic][pj + 2] = v.z;
        lds[ic][pj + 3] = v.w;
    }
    __syncthreads();
    {
        int p = t >> 4, icq = (t & 15) * 4;
        short4 s;
        s.x = lds[icq + 0][p];
        s.y = lds[icq + 1][p];
        s.z = lds[icq + 2][p];
        s.w = lds[icq + 3][p];
        *(short4*)&xb[((size_t)b * PIX + pbase + p) * 64 + icq] = s;
    }
}

// ---------------------------------------------------------------------------
// Encoder FC via MFMA, split-bf16 fp32-equivalent (r30 argmin form, restored).
// part[ks][m][n] = sum_{k in chunk ks} x[m][k] * w[n][k]
// x = a2 fp32 [64m][50176k] (big0); w = efw fp32 [256n][50176k]. Both read
// fp32 and truncation-split into 3 bf16 limbs IN REGISTERS; c2's 6-product
// limb scheme. Post-r30 refinements both regressed (r31 LDS-staging 286.2,
// r32 KS=98 287.1) vs this form's 281.9 — latency-bound structure is at its
// measured local optimum.
// grid = (4 n-blocks of 64, 56 k-chunks of 896), block 256 = 4 waves.
// ---------------------------------------------------------------------------
__global__ __launch_bounds__(256) void enc_fc_mfma_k(const float* __restrict__ x,
                              const float* __restrict__ w,
                              float* __restrict__ part) {
    int tid = threadIdx.x;
    int lane = tid & 63, wv = tid >> 6;
    int prow = lane & 15, kgrp = lane >> 4;
    int nb = blockIdx.x * 64 + wv * 16;
    int ks = blockIdx.y;

    f32x4 acc[4];
    #pragma unroll
    for (int mi = 0; mi < 4; ++mi) acc[mi] = (f32x4){0.f, 0.f, 0.f, 0.f};

    const float* wrow = &w[(size_t)(nb + prow) * FEAT];
    int k0 = ks * KCH;

    for (int kk = 0; kk < KCH; kk += 32) {
        int kof = k0 + kk + kgrp * 8;
        bf16x8 wh, wm, wl;
        {
            float4 wa = *(const float4*)&wrow[kof];
            float4 wb4 = *(const float4*)&wrow[kof + 4];
            split3x8(wa, wb4, wh, wm, wl);
        }
        #pragma unroll
        for (int mi = 0; mi < 4; ++mi) {
            const float* xr = &x[(size_t)(mi * 16 + prow) * FEAT + kof];
            float4 xa = *(const float4*)&xr[0];
            float4 xb4 = *(const float4*)&xr[4];
            bf16x8 ah, am, al;
            split3x8(xa, xb4, ah, am, al);
            // c2's validated 6-product fp32-equivalent sequence
            acc[mi] = __builtin_amdgcn_mfma_f32_16x16x32_bf16(ah, wh, acc[mi], 0, 0, 0);
            acc[mi] = __builtin_amdgcn_mfma_f32_16x16x32_bf16(ah, wm, acc[mi], 0, 0, 0);
            acc[mi] = __builtin_amdgcn_mfma_f32_16x16x32_bf16(am, wh, acc[mi], 0, 0, 0);
            acc[mi] = __builtin_amdgcn_mfma_f32_16x16x32_bf16(ah, wl, acc[mi], 0, 0, 0);
            acc[mi] = __builtin_amdgcn_mfma_f32_16x16x32_bf16(am, wm, acc[mi], 0, 0, 0);
            acc[mi] = __builtin_amdgcn_mfma_f32_16x16x32_bf16(al, wh, acc[mi], 0, 0, 0);
        }
    }

    // part[(ks*BATCH + m)*LATENT + n]; lanes 0-15 write 16 consecutive n (64B).
    #pragma unroll
    for (int mi = 0; mi < 4; ++mi)
        #pragma unroll
        for (int r = 0; r < 4; ++r)
            part[(size_t)(ks * BATCH + mi * 16 + kgrp * 4 + r) * LATENT + nb + prow]
                = acc[mi][r];
}

// grid 64 (m), block 256 (n): z = tanh(sum_ks part + b); emit 2-limb bf16 of
// atanh(z) in [m][k] layout for the MFMA decoder FC.
__global__ void enc_fc_fin_k(const float* __restrict__ part, const float* __restrict__ bias,
                             float* __restrict__ z, short* __restrict__ xah,
                             short* __restrict__ xam) {
    int m = blockIdx.x;
    int n = threadIdx.x;
    int idx = m * 256 + n;
    float a = bias[n];
    for (int ksi = 0; ksi < KS; ++ksi) a += part[(size_t)ksi * BATCH * LATENT + idx];
    float zv = tanhf(a);
    z[idx] = zv;
    float xv = atanhf(zv);
    short h = f2bf(xv);
    xah[idx] = h;
    xam[idx] = f2bf(xv - bf2f(h));
}

// ---------------------------------------------------------------------------
// Hopfield weight
// ---------------------------------------------------------------------------
__global__ void hop_rho_k(const float* __restrict__ ll, float* __restrict__ rho_out) {
    float p = 0.f;
    for (int t = threadIdx.x; t < LABEL * LATENT; t += 256) p += sgnf(ll[t]);
    __shared__ float red[8];
    for (int o = 32; o; o >>= 1) p += __shfl_down(p, o, 64);
    if ((threadIdx.x & 63) == 0) red[threadIdx.x >> 6] = p;
    __syncthreads();
    if (threadIdx.x == 0)
        rho_out[0] = (red[0] + red[1] + red[2] + red[3]) / (float)(LABEL * LATENT);
}

__global__ void hop_w_k(const float* __restrict__ ll, const float* __restrict__ rho_p,
                        float* __restrict__ wout) {
    int i = blockIdx.x, j = threadIdx.x;
    float rho = rho_p[0];
    float acc = 0.f;
    #pragma unroll
    for (int l = 0; l < LABEL; ++l) {
        float a = sgnf(ll[l * LATENT + i]) - rho;
        float b = sgnf(ll[l * LATENT + j]) - rho;
        acc += a * b;
    }
    wout[i * LATENT + j] = (i == j) ? 0.f : acc / 10.f;
}

// ---------------------------------------------------------------------------
// Cluster iteration + cluster softmax head.
// ---------------------------------------------------------------------------
__global__ __launch_bounds__(1024) void cluster_k(const float* __restrict__ z,
                          const float* __restrict__ w,
                          const float* __restrict__ ll, float* __restrict__ out) {
    int b = blockIdx.x;
    int t = threadIdx.x;
    int i = t & 255;
    int q = t >> 8;
    int lane = t & 63;
    int wvid = t >> 6;

    __shared__ float s_sh[LATENT];
    __shared__ float part[1024];
    __shared__ float red[4];
    __shared__ float cflag[4];
    __shared__ int ctl_sh;
    __shared__ float logit[LABEL];

    float wreg[64];
    #pragma unroll
    for (int jj = 0; jj < 64; ++jj)
        wreg[jj] = w[(q * 64 + jj) * LATENT + i];

    float s_cur = 0.f, s_old = 2.f, v = 0.f;
    float e_prev = 0.f;
    if (q == 0) {
        s_cur = sgnf(z[b * LATENT + i]);
        s_sh[i] = s_cur;
    }
    __syncthreads();

    {
        float p0 = 0.f, p1 = 0.f;
        #pragma unroll
        for (int jj = 0; jj < 64; jj += 2) {
            p0 += wreg[jj]     * s_sh[q * 64 + jj];
            p1 += wreg[jj + 1] * s_sh[q * 64 + jj + 1];
        }
        part[t] = p0 + p1;
    }
    __syncthreads();
    if (q == 0) {
        v = part[i] + part[i + 256] + part[i + 512] + part[i + 768];
        float p = s_cur * v;
        #pragma unroll
        for (int o = 32; o; o >>= 1) p += __shfl_down(p, o, 64);
        if (lane == 0) red[wvid] = p;
    }
    __syncthreads();
    if (t == 0) e_prev = -(red[0] + red[1] + red[2] + red[3]);

    for (int it = 0; it < LATENT; ++it) {
        if (q == 0) {
            float ns = sgnf(v);
            unsigned long long m = __ballot(ns == s_old);
            if (lane == 0) cflag[wvid] = (m == ~0ull) ? 1.f : 0.f;
            s_sh[i] = ns;
            s_old = s_cur;
            s_cur = ns;
        }
        __syncthreads();
        {
            float p0 = 0.f, p1 = 0.f;
            #pragma unroll
            for (int jj = 0; jj < 64; jj += 2) {
                p0 += wreg[jj]     * s_sh[q * 64 + jj];
                p1 += wreg[jj + 1] * s_sh[q * 64 + jj + 1];
            }
            part[t] = p0 + p1;
        }
        __syncthreads();
        if (q == 0) {
            v = part[i] + part[i + 256] + part[i + 512] + part[i + 768];
            float p = s_cur * v;
            #pragma unroll
            for (int o = 32; o; o >>= 1) p += __shfl_down(p, o, 64);
            if (lane == 0) red[wvid] = p;
        }
        __syncthreads();
        if (t == 0) {
            float e = -(red[0] + red[1] + red[2] + red[3]);
            int c = 0;
            if (e == e_prev) c = 1;
            else if (it >= 1 && cflag[0] != 0.f && cflag[1] != 0.f &&
                     cflag[2] != 0.f && cflag[3] != 0.f)
                c = (((LATENT - 1 - it) & 1) == 0) ? 2 : 3;
            else e_prev = e;
            ctl_sh = c;
        }
        __syncthreads();
        int c = ctl_sh;
        if (c != 0) {
            if (c == 3 && q == 0) s_sh[i] = s_old;
            break;
        }
    }
    __syncthreads();

    if (wvid < LABEL) {
        float p = 0.f;
        #pragma unroll
        for (int r = 0; r < 4; ++r)
            p += s_sh[r * 64 + lane] * ll[wvid * LATENT + r * 64 + lane];
        #pragma unroll
        for (int o = 32; o; o >>= 1) p += __shfl_down(p, o, 64);
        if (lane == 0) logit[wvid] = p;
    }
    __syncthreads();
    if (t == 0) {
        float mx = logit[0];
        for (int c = 1; c < LABEL; ++c) mx = fmaxf(mx, logit[c]);
        float ex[LABEL];
        float s = 0.f;
        for (int c = 0; c < LABEL; ++c) { ex[c] = expf(logit[c] - mx); s += ex[c]; }
        for (int c = 0; c < LABEL; ++c) out[b * LABEL + c] = ex[c] / s;
    }
}

__device__ __forceinline__ float block_sum256(float p, float* red) {
    __syncthreads();
    for (int o = 32; o; o >>= 1) p += __shfl_down(p, o, 64);
    if ((threadIdx.x & 63) == 0) red[threadIdx.x >> 6] = p;
    __syncthreads();
    return red[0] + red[1] + red[2] + red[3];
}

__global__ void class_k(const float* __restrict__ z, const float* __restrict__ smw,
                        const float* __restrict__ smb, float* __restrict__ out) {
    int b = blockIdx.x;
    int i = threadIdx.x;
    __shared__ float red[8];
    __shared__ float logit[LABEL];
    float zi = z[b * LATENT + i];
    for (int c = 0; c < LABEL; ++c) {
        float p = zi * smw[c * LATENT + i];
        float t = block_sum256(p, red);
        if (i == 0) logit[c] = t + smb[c];
    }
    __syncthreads();
    if (i == 0) {
        float mx = logit[0];
        for (int c = 1; c < LABEL; ++c) mx = fmaxf(mx, logit[c]);
        float ex[LABEL];
        float s = 0.f;
        for (int c = 0; c < LABEL; ++c) { ex[c] = expf(logit[c] - mx); s += ex[c]; }
        for (int c = 0; c < LABEL; ++c) out[b * LABEL + c] = ex[c] / s;
    }
}

// ---------------------------------------------------------------------------
// Decoder FC via MFMA: y16[m][n] = bf16( (xh+xm)[m][k] @ bf16(w)[n][k] + b ).
// ---------------------------------------------------------------------------
__global__ __launch_bounds__(256) void dec_fc_mfma_k(const short* __restrict__ xah,
                         const short* __restrict__ xam,
                         const float* __restrict__ w,
                         const float* __restrict__ bias, short* __restrict__ y16) {
    int tid = threadIdx.x;
    int lane = tid & 63, wv = tid >> 6;
    int prow = lane & 15, kgrp = lane >> 4;
    int n0 = blockIdx.x * 64;
    int nb = n0 + wv * 16;

    f32x4 acc[4];
    #pragma unroll
    for (int mi = 0; mi < 4; ++mi) acc[mi] = (f32x4){0.f, 0.f, 0.f, 0.f};

    for (int kc = 0; kc < 8; ++kc) {
        int kof = kc * 32 + kgrp * 8;
        const float* wp = &w[(size_t)(nb + prow) * LATENT + kof];
        float4 w0 = *(const float4*)&wp[0];
        float4 w1 = *(const float4*)&wp[4];
        bf16x8 bf;
        bf[0] = f2bf(w0.x); bf[1] = f2bf(w0.y); bf[2] = f2bf(w0.z); bf[3] = f2bf(w0.w);
        bf[4] = f2bf(w1.x); bf[5] = f2bf(w1.y); bf[6] = f2bf(w1.z); bf[7] = f2bf(w1.w);
        #pragma unroll
        for (int mi = 0; mi < 4; ++mi) {
            bf16x8 ah = *(const bf16x8*)&xah[(mi * 16 + prow) * LATENT + kof];
            bf16x8 am = *(const bf16x8*)&xam[(mi * 16 + prow) * LATENT + kof];
            acc[mi] = __builtin_amdgcn_mfma_f32_16x16x32_bf16(ah, bf, acc[mi], 0, 0, 0);
            acc[mi] = __builtin_amdgcn_mfma_f32_16x16x32_bf16(am, bf, acc[mi], 0, 0, 0);
        }
    }

    // epilogue: stage bf16 tile [64m][64n] in LDS, coalesced 64B-group stores
    __shared__ short ot[64 * 72];   // stride 72 shorts = 144B (16B-aligned rows)
    float bv = bias[nb + prow];
    #pragma unroll
    for (int mi = 0; mi < 4; ++mi)
        #pragma unroll
        for (int r = 0; r < 4; ++r) {
            int m = mi * 16 + kgrp * 4 + r;
            ot[m * 72 + wv * 16 + prow] = f2bf(acc[mi][r] + bv);
        }
    __syncthreads();
    int m = tid >> 2, q = tid & 3;
    #pragma unroll
    for (int i = 0; i < 2; ++i) {
        *(int4*)&y16[(size_t)m * FEAT + n0 + i * 32 + q * 8] =
            *(int4*)&ot[m * 72 + i * 32 + q * 8];
    }
}

// ---------------------------------------------------------------------------
extern "C" void kernel_launch(void* const* d_in, const int* in_sizes, int n_in,
                              void* d_out, int out_size, void* d_ws, size_t ws_size,
                              hipStream_t stream) {
    const float* images   = (const float*)d_in[0];
    const float* c1w      = (const float*)d_in[1];
    const float* c1b      = (const float*)d_in[2];
    const float* c2w      = (const float*)d_in[3];
    const float* c2b      = (const float*)d_in[4];
    const float* efw      = (const float*)d_in[5];
    const float* efb      = (const float*)d_in[6];
    const float* dfw      = (const float*)d_in[7];
    const float* dfb      = (const float*)d_in[8];
    const float* ct2w     = (const float*)d_in[9];
    const float* ct2b     = (const float*)d_in[10];
    const float* ct1w     = (const float*)d_in[11];
    const float* ct1b     = (const float*)d_in[12];
    const float* smw      = (const float*)d_in[13];
    const float* smb      = (const float*)d_in[14];
    const float* ll       = (const float*)d_in[15];

    float* out = (float*)d_out;
    float* ws  = (float*)d_ws;

    // ws layout (floats)
    float* big0 = ws;                                  // 3211264 (a2; y16 bf16 aliases after enc)
    float* big1 = ws + 3211264;                        // 1605632 (a1 / ct2 out)
    float* z    = ws + 3211264 + 1605632 + 458752;     // 16384
    float* whop = z + BATCH * LATENT;                  // 65536
    float* rho  = whop + LATENT * LATENT;              // 4
    float* xsa  = rho + 4;                             // 16384 (holds xah/xam shorts)
    short* xah  = (short*)xsa;                         // 16384 shorts
    short* xam  = xah + 16384;                         // 16384 shorts
    short* xbf  = (short*)(xsa + 16384);               // 3211264 shorts region
    short* wbf  = (short*)(xsa + 16384 + 1605632);     // 51200 shorts (ct2 w)
    short* xh3  = xbf;                                 // conv2 hi limb (dead before part)
    short* xm3  = xbf + 1605632;                       // conv2 mid limb
    short* xl3  = (short*)(xsa + 16384 + 1605632 + 25600);   // 1605632 shorts
    short* wb3  = xl3 + 1605632;                       // 153600 shorts
    short* y16  = (short*)big0;                        // big0 dead after enc_fc
    // enc_fc partials: 56*16384 = 917504 floats in the xbf region (holds
    // 1605632 floats — fits). Lifetimes disjoint: xh3/xm3 dead after c2_mfma;
    // ct2's xbf written after part is dead (post enc_fc_fin).
    float* part = (float*)xbf;

    // encoder (conv1 fp32; conv2 + enc_fc split-bf16 MFMA = fp32-equivalent)
    conv5_k<4,0><<<dim3(BATCH, 8), 256, 0, stream>>>(images, c1w, c1b, big1, 1, 32, 1);
    wprep3_k<<<200, 256, 0, stream>>>(c2w, wb3);
    xsplit3_k<<<dim3(BATCH, 49), 256, 0, stream>>>(big1, xh3, xm3, xl3);
    c2_mfma_k<<<dim3(BATCH, 13), 64, 0, stream>>>(xh3, xm3, xl3, wb3, c2b, big0);
    enc_fc_mfma_k<<<dim3(4, KS), 256, 0, stream>>>(big0, efw, part);
    enc_fc_fin_k<<<BATCH, 256, 0, stream>>>(part, efb, z, xah, xam);

    // hopfield
    hop_rho_k<<<1, 256, 0, stream>>>(ll, rho);
    hop_w_k<<<LATENT, 256, 0, stream>>>(ll, rho, whop);
    cluster_k<<<BATCH, 1024, 0, stream>>>(z, whop, ll, out);           // cluster_probs
    class_k<<<BATCH, 256, 0, stream>>>(z, smw, smb, out + 640);        // class_probs

    // decoder (dec_fc MFMA bf16-out; ct2 bf16 MFMA)
    wprep_k<<<200, 256, 0, stream>>>(ct2w, wbf);
    dec_fc_mfma_k<<<FEAT / 64, 256, 0, stream>>>(xah, xam, dfw, dfb, y16);
    xpose16_k<<<dim3(BATCH, 49), 256, 0, stream>>>(y16, xbf);
    ct2_mfma_k<<<dim3(BATCH, 49), 64, 0, stream>>>(xbf, wbf, ct2b, big1);
    conv5_k<1,1><<<dim3(BATCH, 1), 256, 0, stream>>>(big1, ct1w, ct1b, out + 1280, 32, 1, 0);
}